// Round 2
// baseline (497.162 us; speedup 1.0000x reference)
//
#include <hip/hip_runtime.h>
#include <hip/hip_bf16.h>
#include <stdint.h>

#define N_NODES 100000
#define C 128
#define NET 7
#define NSAMP 2
#define E_EDGES 700000
#define BM 32

// ---------- threefry2x32 (JAX) ----------
struct TF2 { uint32_t a, b; };

__host__ __device__ constexpr uint32_t rotl32c(uint32_t v, int r) {
    return (v << r) | (v >> (32 - r));
}

__host__ __device__ constexpr TF2 threefry2x32(uint32_t k0, uint32_t k1,
                                               uint32_t x0, uint32_t x1) {
    const uint32_t ks0 = k0, ks1 = k1, ks2 = 0x1BD11BDAu ^ k0 ^ k1;
    x0 += ks0; x1 += ks1;
#define RND(r) { x0 += x1; x1 = rotl32c(x1, (r)); x1 ^= x0; }
    RND(13) RND(15) RND(26) RND(6)
    x0 += ks1; x1 += ks2 + 1u;
    RND(17) RND(29) RND(16) RND(24)
    x0 += ks2; x1 += ks0 + 2u;
    RND(13) RND(15) RND(26) RND(6)
    x0 += ks0; x1 += ks1 + 3u;
    RND(17) RND(29) RND(16) RND(24)
    x0 += ks1; x1 += ks2 + 4u;
    RND(13) RND(15) RND(26) RND(6)
    x0 += ks2; x1 += ks0 + 5u;
#undef RND
    return TF2{x0, x1};
}

// k2 = split(key(42), 2)[1]  (fold-like/partitionable split: block at counter (0,1))
constexpr TF2 K2 = threefry2x32(0u, 42u, 0u, 1u);

// lower_bits[f] for random_bits(k2, 32, (S,2)): XOR of both output words, counter (0, f)
__device__ __forceinline__ uint32_t jax_bits32(uint32_t f) {
    TF2 o = threefry2x32(K2.a, K2.b, 0u, f);
    return o.a ^ o.b;
}

// ---------- stage 1: histogram + starts ----------
__global__ void zero_counts(int* counts, int S) {
    int i = blockIdx.x * blockDim.x + threadIdx.x;
    if (i < S) counts[i] = 0;
}

__global__ void hist_starts(const int* __restrict__ idx, int* __restrict__ counts,
                            int* __restrict__ starts, int E) {
    int e = blockIdx.x * blockDim.x + threadIdx.x;
    if (e >= E) return;
    int s = idx[e];
    atomicAdd(&counts[s], 1);
    if (e == 0 || idx[e - 1] != s) starts[s] = e;
}

// ---------- stage 2: Monte-Carlo edge sampling -> per-slot node pair ----------
__global__ void make_pairs(const int* __restrict__ counts, const int* __restrict__ starts,
                           const int* __restrict__ col, int2* __restrict__ pairs, int S) {
    int s = blockIdx.x * blockDim.x + threadIdx.x;
    if (s >= S) return;
    if (s % NET == NET - 1) {               // self slot: overwritten with x[node]
        int node = s / NET;
        pairs[s] = make_int2(node, node);   // mean(x[node], x[node]) == x[node]
        return;
    }
    int cnt = counts[s];
    if (cnt <= 0) {
        pairs[s] = make_int2(-1, -1);       // empty slot -> zeros
        return;
    }
    int st = starts[s];
    // rel[s][k] = (bits(2s+k) & 0x3FFFFFFF) % cnt   (multiplier term provably 0)
    uint32_t b0 = jax_bits32((uint32_t)s * 2u + 0u) & 0x3FFFFFFFu;
    uint32_t b1 = jax_bits32((uint32_t)s * 2u + 1u) & 0x3FFFFFFFu;
    int r0 = (int)(b0 % (uint32_t)cnt);
    int r1 = (int)(b1 % (uint32_t)cnt);
    pairs[s] = make_int2(col[st + r0], col[st + r1]);
}

// ---------- stage 3: fused gather + fp32 GEMM ----------
// out[n][c] = sum_{et,k} colrow(n*7+et)[k] * W[et*128+k][c]
__global__ __launch_bounds__(256) void fused_gemm(const float* __restrict__ x,
                                                  const int2* __restrict__ pairs,
                                                  const float* __restrict__ W,
                                                  float* __restrict__ out) {
    __shared__ float Alds[BM][C];
    const int nb  = blockIdx.x * BM;
    const int tid = threadIdx.x;
    const int c   = tid & (C - 1);
    const int rg  = tid >> 7;

    float acc[16];
#pragma unroll
    for (int i = 0; i < 16; i++) acc[i] = 0.f;

    for (int et = 0; et < NET; ++et) {
        __syncthreads();
        // Build A tile: row r of tile = slot (nb+r)*7+et; 8 threads per row, 16 floats each.
        {
            int r = tid >> 3;
            int j = tid & 7;
            int2 p = pairs[(size_t)(nb + r) * NET + et];
            float4* dst = (float4*)(&Alds[r][j * 16]);
            if (p.x < 0) {
                float4 z = make_float4(0.f, 0.f, 0.f, 0.f);
                dst[0] = z; dst[1] = z; dst[2] = z; dst[3] = z;
            } else {
                const float4* x0 = (const float4*)(x + (size_t)p.x * C) + j * 4;
                const float4* x1 = (const float4*)(x + (size_t)p.y * C) + j * 4;
#pragma unroll
                for (int m = 0; m < 4; m++) {
                    float4 a = x0[m], b = x1[m];
                    dst[m] = make_float4(0.5f * (a.x + b.x), 0.5f * (a.y + b.y),
                                         0.5f * (a.z + b.z), 0.5f * (a.w + b.w));
                }
            }
        }
        __syncthreads();

        const float* Wp = W + (size_t)et * C * C + c;
#pragma unroll 2
        for (int k4 = 0; k4 < C; k4 += 4) {
            float4 a[16];
#pragma unroll
            for (int i = 0; i < 16; i++)
                a[i] = *(const float4*)&Alds[rg + 2 * i][k4];   // wave-uniform broadcast
            float w0 = Wp[(size_t)(k4 + 0) * C];
            float w1 = Wp[(size_t)(k4 + 1) * C];
            float w2 = Wp[(size_t)(k4 + 2) * C];
            float w3 = Wp[(size_t)(k4 + 3) * C];
#pragma unroll
            for (int i = 0; i < 16; i++) {
                acc[i] = fmaf(a[i].x, w0, acc[i]);
                acc[i] = fmaf(a[i].y, w1, acc[i]);
                acc[i] = fmaf(a[i].z, w2, acc[i]);
                acc[i] = fmaf(a[i].w, w3, acc[i]);
            }
        }
    }

#pragma unroll
    for (int i = 0; i < 16; i++) {
        int row = nb + rg + 2 * i;
        if (row < N_NODES) out[(size_t)row * C + c] = acc[i];
    }
}

extern "C" void kernel_launch(void* const* d_in, const int* in_sizes, int n_in,
                              void* d_out, int out_size, void* d_ws, size_t ws_size,
                              hipStream_t stream) {
    const float* x   = (const float*)d_in[0];
    const int*   col = (const int*)d_in[1];
    const int*   idx = (const int*)d_in[2];
    const float* W   = (const float*)d_in[3];
    float* out = (float*)d_out;

    const int S = N_NODES * NET;
    int*  counts = (int*)d_ws;
    int*  starts = counts + S;
    int2* pairs  = (int2*)(starts + S);

    zero_counts<<<(S + 255) / 256, 256, 0, stream>>>(counts, S);
    hist_starts<<<(E_EDGES + 255) / 256, 256, 0, stream>>>(idx, counts, starts, E_EDGES);
    make_pairs<<<(S + 255) / 256, 256, 0, stream>>>(counts, starts, col, pairs, S);
    fused_gemm<<<N_NODES / BM, 256, 0, stream>>>(x, pairs, W, out);
}

// Round 3
// 114.006 us; speedup vs baseline: 4.3608x; 4.3608x over previous
//
#include <hip/hip_runtime.h>
#include <hip/hip_bf16.h>
#include <stdint.h>

#define N_NODES 100000
#define C 128
#define NET 7
#define E_EDGES 700000
#define LDW 136   // LDS row stride in bf16 elements (128 + 8 pad = 272B, breaks bank conflicts)

typedef __attribute__((ext_vector_type(8))) short short8;
typedef __attribute__((ext_vector_type(4))) float f32x4;
typedef __attribute__((ext_vector_type(4))) unsigned int uint4v;

// ---------- threefry2x32 (JAX) ----------
struct TF2 { uint32_t a, b; };

__host__ __device__ constexpr uint32_t rotl32c(uint32_t v, int r) {
    return (v << r) | (v >> (32 - r));
}

__host__ __device__ constexpr TF2 threefry2x32(uint32_t k0, uint32_t k1,
                                               uint32_t x0, uint32_t x1) {
    const uint32_t ks0 = k0, ks1 = k1, ks2 = 0x1BD11BDAu ^ k0 ^ k1;
    x0 += ks0; x1 += ks1;
#define RND(r) { x0 += x1; x1 = rotl32c(x1, (r)); x1 ^= x0; }
    RND(13) RND(15) RND(26) RND(6)
    x0 += ks1; x1 += ks2 + 1u;
    RND(17) RND(29) RND(16) RND(24)
    x0 += ks2; x1 += ks0 + 2u;
    RND(13) RND(15) RND(26) RND(6)
    x0 += ks0; x1 += ks1 + 3u;
    RND(17) RND(29) RND(16) RND(24)
    x0 += ks1; x1 += ks2 + 4u;
    RND(13) RND(15) RND(26) RND(6)
    x0 += ks2; x1 += ks0 + 5u;
#undef RND
    return TF2{x0, x1};
}

constexpr TF2 K2 = threefry2x32(0u, 42u, 0u, 1u);  // split(key(42),2)[1]

__device__ __forceinline__ uint32_t jax_bits32(uint32_t f) {
    TF2 o = threefry2x32(K2.a, K2.b, 0u, f);
    return o.a ^ o.b;
}

// bf16 round-to-nearest-even pack
__device__ __forceinline__ unsigned short f2bf(float f) {
    uint32_t u = __float_as_uint(f);
    u += 0x7fffu + ((u >> 16) & 1u);
    return (unsigned short)(u >> 16);
}

// avg two packed-bf16 dwords (2 elements each) -> packed bf16 dword
__device__ __forceinline__ uint32_t avg2bf16(uint32_t a, uint32_t b) {
    float alo = __uint_as_float(a << 16);
    float ahi = __uint_as_float(a & 0xffff0000u);
    float blo = __uint_as_float(b << 16);
    float bhi = __uint_as_float(b & 0xffff0000u);
    uint32_t ulo = __float_as_uint((alo + blo) * 0.5f);
    uint32_t uhi = __float_as_uint((ahi + bhi) * 0.5f);
    ulo = (ulo + 0x7fffu + ((ulo >> 16) & 1u)) >> 16;
    uhi = (uhi + 0x7fffu + ((uhi >> 16) & 1u)) & 0xffff0000u;
    return uhi | ulo;
}

// ---------- stage 1: histogram + starts ----------
__global__ void zero_counts(int* counts, int S) {
    int i = blockIdx.x * blockDim.x + threadIdx.x;
    if (i < S) counts[i] = 0;
}

__global__ void hist_starts(const int* __restrict__ idx, int* __restrict__ counts,
                            int* __restrict__ starts, int E) {
    int e = blockIdx.x * blockDim.x + threadIdx.x;
    if (e >= E) return;
    int s = idx[e];
    atomicAdd(&counts[s], 1);
    if (e == 0 || idx[e - 1] != s) starts[s] = e;
}

// ---------- stage 2: sampling -> per-slot pair ----------
// encodings: (-1,-1)=empty/zeros; (n,-2)=single row n (exact copy); (n0,n1)=avg
__global__ void make_pairs(const int* __restrict__ counts, const int* __restrict__ starts,
                           const int* __restrict__ col, int2* __restrict__ pairs, int S) {
    int s = blockIdx.x * blockDim.x + threadIdx.x;
    if (s >= S) return;
    if (s % NET == NET - 1) {                  // self slot overwritten with x[node]
        pairs[s] = make_int2(s / NET, -2);
        return;
    }
    int cnt = counts[s];
    if (cnt <= 0) { pairs[s] = make_int2(-1, -1); return; }
    int st = starts[s];
    uint32_t b0 = jax_bits32((uint32_t)s * 2u + 0u) & 0x3FFFFFFFu;
    uint32_t b1 = jax_bits32((uint32_t)s * 2u + 1u) & 0x3FFFFFFFu;
    int c0 = col[st + (int)(b0 % (uint32_t)cnt)];
    int c1 = col[st + (int)(b1 % (uint32_t)cnt)];
    pairs[s] = (c0 == c1) ? make_int2(c0, -2) : make_int2(c0, c1);  // avg(a,a)==a exactly
}

// ---------- conversions ----------
__global__ void cvt_x(const float* __restrict__ x, unsigned short* __restrict__ xb) {
    int i = blockIdx.x * 256 + threadIdx.x;          // 8 elements per thread
    const float4* src = (const float4*)x + (size_t)i * 2;
    float4 a = src[0], b = src[1];
    union { unsigned short u[8]; uint4v v; } o;
    o.u[0] = f2bf(a.x); o.u[1] = f2bf(a.y); o.u[2] = f2bf(a.z); o.u[3] = f2bf(a.w);
    o.u[4] = f2bf(b.x); o.u[5] = f2bf(b.y); o.u[6] = f2bf(b.z); o.u[7] = f2bf(b.w);
    ((uint4v*)xb)[i] = o.v;
}

// Wt[et][n][k] (bf16) from W[et*128+k][n] (fp32)
__global__ void cvt_w(const float* __restrict__ W, unsigned short* __restrict__ Wt) {
    int t = blockIdx.x * 256 + threadIdx.x;
    if (t >= NET * 128 * 16) return;
    int k8 = t & 15, n = (t >> 4) & 127, et = t >> 11;
    union { unsigned short u[8]; uint4v v; } o;
#pragma unroll
    for (int j = 0; j < 8; j++)
        o.u[j] = f2bf(W[(size_t)(et * 128 + k8 * 8 + j) * 128 + n]);
    ((uint4v*)Wt)[(size_t)(et * 128 + n) * 16 + k8] = o.v;
}

// ---------- stage 3: fused gather + bf16 MFMA GEMM ----------
// 128x128 output tile/block; 4 waves, each 64x64 (4x4 frags of 16x16x32)
__global__ __launch_bounds__(256) void fused_mfma(const unsigned short* __restrict__ xb,
                                                  const int2* __restrict__ pairs,
                                                  const unsigned short* __restrict__ Wt,
                                                  float* __restrict__ out) {
    __shared__ unsigned short Alds[128 * LDW];
    __shared__ unsigned short Blds[128 * LDW];
    const int tid  = threadIdx.x;
    const int nb   = blockIdx.x * 128;
    const int wave = tid >> 6, lane = tid & 63;
    const int wr   = wave >> 1, wc = wave & 1;
    const int lr   = lane & 15, lg = lane >> 4;

    f32x4 acc[4][4];
#pragma unroll
    for (int i = 0; i < 4; i++)
#pragma unroll
        for (int j = 0; j < 4; j++) acc[i][j] = (f32x4)0.f;

    const int r = tid >> 1, h = tid & 1;     // staging: thread covers row r, half h (64 el)
    const int arow = nb + r;

    for (int et = 0; et < NET; ++et) {
        __syncthreads();
        // --- A stage: row r of tile = slot (nb+r)*7+et, avg of two x rows in bf16 ---
        {
            uint4v* dst = (uint4v*)&Alds[r * LDW + h * 64];
            int2 p = make_int2(-1, -1);
            if (arow < N_NODES) p = pairs[arow * NET + et];
            if (p.x < 0) {
                uint4v z = {0u, 0u, 0u, 0u};
#pragma unroll
                for (int m = 0; m < 8; m++) dst[m] = z;
            } else if (p.y < 0) {
                const uint4v* s0 = (const uint4v*)(xb + (size_t)p.x * C + h * 64);
#pragma unroll
                for (int m = 0; m < 8; m++) dst[m] = s0[m];
            } else {
                const uint4v* s0 = (const uint4v*)(xb + (size_t)p.x * C + h * 64);
                const uint4v* s1 = (const uint4v*)(xb + (size_t)p.y * C + h * 64);
#pragma unroll
                for (int m = 0; m < 8; m++) {
                    uint4v a = s0[m], b = s1[m], o;
                    o.x = avg2bf16(a.x, b.x);
                    o.y = avg2bf16(a.y, b.y);
                    o.z = avg2bf16(a.z, b.z);
                    o.w = avg2bf16(a.w, b.w);
                    dst[m] = o;
                }
            }
        }
        // --- B stage: Wt[et] 128x128 bf16 -> LDS (linear copy, coalesced) ---
        {
            const uint4v* bs = (const uint4v*)(Wt + (size_t)et * 16384);
#pragma unroll
            for (int i = 0; i < 8; i++) {
                int q = tid + i * 256;
                int rb = q >> 4, cw = q & 15;
                *(uint4v*)&Blds[rb * LDW + cw * 8] = bs[q];
            }
        }
        __syncthreads();

        // --- MFMA: 4 k-steps of 32 ---
        const unsigned short* Abase = &Alds[(wr * 64 + lr) * LDW + lg * 8];
        const unsigned short* Bbase = &Blds[(wc * 64 + lr) * LDW + lg * 8];
#pragma unroll
        for (int ks = 0; ks < 4; ++ks) {
            short8 af[4], bf[4];
#pragma unroll
            for (int fm = 0; fm < 4; fm++)
                af[fm] = *(const short8*)(Abase + fm * 16 * LDW + ks * 32);
#pragma unroll
            for (int fn = 0; fn < 4; fn++)
                bf[fn] = *(const short8*)(Bbase + fn * 16 * LDW + ks * 32);
#pragma unroll
            for (int fm = 0; fm < 4; fm++)
#pragma unroll
                for (int fn = 0; fn < 4; fn++)
                    acc[fm][fn] = __builtin_amdgcn_mfma_f32_16x16x32_bf16(
                        af[fm], bf[fn], acc[fm][fn], 0, 0, 0);
        }
    }

    // --- epilogue: D layout col=lane&15, row=(lane>>4)*4+reg ---
#pragma unroll
    for (int fm = 0; fm < 4; fm++) {
        int row0 = nb + wr * 64 + fm * 16 + lg * 4;
#pragma unroll
        for (int fn = 0; fn < 4; fn++) {
            int colo = wc * 64 + fn * 16 + lr;
#pragma unroll
            for (int j = 0; j < 4; j++)
                if (row0 + j < N_NODES)
                    out[(size_t)(row0 + j) * C + colo] = acc[fm][fn][j];
        }
    }
}

// ---------- fallback fp32 path (only if ws too small for bf16 buffers) ----------
__global__ __launch_bounds__(256) void fused_gemm_fp32(const float* __restrict__ x,
                                                       const int2* __restrict__ pairs,
                                                       const float* __restrict__ W,
                                                       float* __restrict__ out) {
    __shared__ float Alds[32][C];
    const int nb = blockIdx.x * 32, tid = threadIdx.x;
    const int c = tid & (C - 1), rg = tid >> 7;
    float acc[16];
#pragma unroll
    for (int i = 0; i < 16; i++) acc[i] = 0.f;
    for (int et = 0; et < NET; ++et) {
        __syncthreads();
        {
            int r = tid >> 3, j = tid & 7;
            int2 p = pairs[(size_t)(nb + r) * NET + et];
            float4* dst = (float4*)(&Alds[r][j * 16]);
            if (p.x < 0) {
                float4 z = make_float4(0.f, 0.f, 0.f, 0.f);
                dst[0] = z; dst[1] = z; dst[2] = z; dst[3] = z;
            } else {
                int py = p.y < 0 ? p.x : p.y;
                const float4* x0 = (const float4*)(x + (size_t)p.x * C) + j * 4;
                const float4* x1 = (const float4*)(x + (size_t)py * C) + j * 4;
#pragma unroll
                for (int m = 0; m < 4; m++) {
                    float4 a = x0[m], b = x1[m];
                    dst[m] = make_float4(0.5f * (a.x + b.x), 0.5f * (a.y + b.y),
                                         0.5f * (a.z + b.z), 0.5f * (a.w + b.w));
                }
            }
        }
        __syncthreads();
        const float* Wp = W + (size_t)et * C * C + c;
#pragma unroll 2
        for (int k4 = 0; k4 < C; k4 += 4) {
            float4 a[16];
#pragma unroll
            for (int i = 0; i < 16; i++) a[i] = *(const float4*)&Alds[rg + 2 * i][k4];
            float w0 = Wp[(size_t)(k4 + 0) * C], w1 = Wp[(size_t)(k4 + 1) * C];
            float w2 = Wp[(size_t)(k4 + 2) * C], w3 = Wp[(size_t)(k4 + 3) * C];
#pragma unroll
            for (int i = 0; i < 16; i++) {
                acc[i] = fmaf(a[i].x, w0, acc[i]); acc[i] = fmaf(a[i].y, w1, acc[i]);
                acc[i] = fmaf(a[i].z, w2, acc[i]); acc[i] = fmaf(a[i].w, w3, acc[i]);
            }
        }
    }
#pragma unroll
    for (int i = 0; i < 16; i++) {
        int row = nb + rg + 2 * i;
        if (row < N_NODES) out[(size_t)row * C + c] = acc[i];
    }
}

extern "C" void kernel_launch(void* const* d_in, const int* in_sizes, int n_in,
                              void* d_out, int out_size, void* d_ws, size_t ws_size,
                              hipStream_t stream) {
    const float* x   = (const float*)d_in[0];
    const int*   col = (const int*)d_in[1];
    const int*   idx = (const int*)d_in[2];
    const float* W   = (const float*)d_in[3];
    float* out = (float*)d_out;

    const int S = N_NODES * NET;
    int*  counts = (int*)d_ws;
    int*  starts = counts + S;
    int2* pairs  = (int2*)(starts + S);
    unsigned short* xb = (unsigned short*)(pairs + S);        // byte off 11.2e6 (16B aligned)
    unsigned short* Wt = xb + (size_t)N_NODES * C;            // byte off 36.8e6

    const size_t ws_needed = (size_t)(4 + 4 + 8) * S + (size_t)N_NODES * C * 2
                           + (size_t)NET * C * C * 2;

    zero_counts<<<(S + 255) / 256, 256, 0, stream>>>(counts, S);
    hist_starts<<<(E_EDGES + 255) / 256, 256, 0, stream>>>(idx, counts, starts, E_EDGES);
    make_pairs<<<(S + 255) / 256, 256, 0, stream>>>(counts, starts, col, pairs, S);

    if (ws_size >= ws_needed) {
        cvt_x<<<(N_NODES * C / 8 + 255) / 256, 256, 0, stream>>>(x, xb);
        cvt_w<<<(NET * 128 * 16 + 255) / 256, 256, 0, stream>>>(W, Wt);
        fused_mfma<<<(N_NODES + 127) / 128, 256, 0, stream>>>(xb, pairs, Wt, out);
    } else {
        fused_gemm_fp32<<<(N_NODES + 31) / 32, 256, 0, stream>>>(x, pairs, W, out);
    }
}

// Round 4
// 99.092 us; speedup vs baseline: 5.0172x; 1.1505x over previous
//
#include <hip/hip_runtime.h>
#include <hip/hip_bf16.h>
#include <stdint.h>

#define N_NODES 100000
#define C 128
#define NET 7
#define E_EDGES 700000
#define S_SLOTS (N_NODES * NET)
#define BM 64
#define LDW 136                 // row stride in bf16 el: 272B = 17*16 (aligned, bank-staggered)
#define NB_CVTX 6250            // 100000*128/8/256
#define NB_CVTW 56              // 7*8*4*64/256
#define NB_PAIRS ((S_SLOTS + 255) / 256)

typedef __attribute__((ext_vector_type(8))) short short8;
typedef __attribute__((ext_vector_type(4))) float f32x4;
typedef __attribute__((ext_vector_type(4))) unsigned int uint4v;

// ---------- threefry2x32 (JAX), verified round 2 ----------
struct TF2 { uint32_t a, b; };

__host__ __device__ constexpr uint32_t rotl32c(uint32_t v, int r) {
    return (v << r) | (v >> (32 - r));
}

__host__ __device__ constexpr TF2 threefry2x32(uint32_t k0, uint32_t k1,
                                               uint32_t x0, uint32_t x1) {
    const uint32_t ks0 = k0, ks1 = k1, ks2 = 0x1BD11BDAu ^ k0 ^ k1;
    x0 += ks0; x1 += ks1;
#define RND(r) { x0 += x1; x1 = rotl32c(x1, (r)); x1 ^= x0; }
    RND(13) RND(15) RND(26) RND(6)
    x0 += ks1; x1 += ks2 + 1u;
    RND(17) RND(29) RND(16) RND(24)
    x0 += ks2; x1 += ks0 + 2u;
    RND(13) RND(15) RND(26) RND(6)
    x0 += ks0; x1 += ks1 + 3u;
    RND(17) RND(29) RND(16) RND(24)
    x0 += ks1; x1 += ks2 + 4u;
    RND(13) RND(15) RND(26) RND(6)
    x0 += ks2; x1 += ks0 + 5u;
#undef RND
    return TF2{x0, x1};
}

constexpr TF2 K2 = threefry2x32(0u, 42u, 0u, 1u);  // split(key(42),2)[1]

__device__ __forceinline__ uint32_t jax_bits32(uint32_t f) {
    TF2 o = threefry2x32(K2.a, K2.b, 0u, f);
    return o.a ^ o.b;
}

// bf16 round-to-nearest-even pack
__device__ __forceinline__ unsigned short f2bf(float f) {
    uint32_t u = __float_as_uint(f);
    u += 0x7fffu + ((u >> 16) & 1u);
    return (unsigned short)(u >> 16);
}

// sum two packed-bf16 dwords -> packed bf16 (truncation pack; x0.5 folded into Wf)
__device__ __forceinline__ uint32_t sumpack(uint32_t a, uint32_t b) {
    float alo = __uint_as_float(a << 16);
    float ahi = __uint_as_float(a & 0xffff0000u);
    float blo = __uint_as_float(b << 16);
    float bhi = __uint_as_float(b & 0xffff0000u);
    return (__float_as_uint(ahi + bhi) & 0xffff0000u) | (__float_as_uint(alo + blo) >> 16);
}

// ---------- prep: cvt_x || cvt_w(frag-major, x0.5) || make_pairs(binary search) ----------
__global__ __launch_bounds__(256) void prep(const float* __restrict__ x,
                                            const int* __restrict__ col,
                                            const int* __restrict__ idx,
                                            const float* __restrict__ W,
                                            unsigned short* __restrict__ xb,
                                            unsigned short* __restrict__ Wf,
                                            int2* __restrict__ pairs) {
    const int b = blockIdx.x;
    if (b < NB_CVTX) {
        // x fp32 -> bf16, 8 el/thread
        int i = b * 256 + threadIdx.x;
        const float4* src = (const float4*)x + (size_t)i * 2;
        float4 a = src[0], v = src[1];
        union { unsigned short u[8]; uint4v q; } o;
        o.u[0] = f2bf(a.x); o.u[1] = f2bf(a.y); o.u[2] = f2bf(a.z); o.u[3] = f2bf(a.w);
        o.u[4] = f2bf(v.x); o.u[5] = f2bf(v.y); o.u[6] = f2bf(v.z); o.u[7] = f2bf(v.w);
        ((uint4v*)xb)[i] = o.q;
    } else if (b < NB_CVTX + NB_CVTW) {
        // W -> Wf[(et*8+n16)*4+ks][lane][8] = 0.5 * W[(et*128+k)*128 + n]
        int t = (b - NB_CVTX) * 256 + threadIdx.x;   // < 14336
        int l = t & 63, ks = (t >> 6) & 3, n16 = (t >> 8) & 7, et = t >> 11;
        int n = n16 * 16 + (l & 15);
        int k0 = ks * 32 + (l >> 4) * 8;
        union { unsigned short u[8]; uint4v q; } o;
#pragma unroll
        for (int j = 0; j < 8; j++)
            o.u[j] = f2bf(0.5f * W[(size_t)(et * 128 + k0 + j) * 128 + n]);
        ((uint4v*)Wf)[t] = o.q;
    } else {
        // per-slot sampling; counts/starts via binary search on sorted idx
        int s = (b - NB_CVTX - NB_CVTW) * 256 + threadIdx.x;
        if (s >= S_SLOTS) return;
        if (s % NET == NET - 1) {                    // self slot: x[node] = (x+x)*0.5W
            int node = s / NET;
            pairs[s] = make_int2(node, node);
            return;
        }
        int lo, hi;
        { int l = 0, r = E_EDGES;
          while (l < r) { int m = (l + r) >> 1; if (idx[m] < s) l = m + 1; else r = m; }
          lo = l; }
        { int l = lo, r = E_EDGES;
          while (l < r) { int m = (l + r) >> 1; if (idx[m] < s + 1) l = m + 1; else r = m; }
          hi = l; }
        int cnt = hi - lo;
        if (cnt <= 0) { pairs[s] = make_int2(-1, -1); return; }
        uint32_t b0 = jax_bits32((uint32_t)s * 2u + 0u) & 0x3FFFFFFFu;
        uint32_t b1 = jax_bits32((uint32_t)s * 2u + 1u) & 0x3FFFFFFFu;
        pairs[s] = make_int2(col[lo + (int)(b0 % (uint32_t)cnt)],
                             col[lo + (int)(b1 % (uint32_t)cnt)]);
    }
}

// ---------- fused: gather(sum) + bf16 MFMA, A double-buffered, B from L2 ----------
// 64x128 tile/block, 4 waves each 32x64 (2x4 frags of 16x16x32)
__global__ __launch_bounds__(256, 3) void fused_mfma(const unsigned short* __restrict__ xb,
                                                     const int2* __restrict__ pairs,
                                                     const unsigned short* __restrict__ Wf,
                                                     float* __restrict__ out) {
    __shared__ unsigned short Alds[2][BM * LDW];
    const int tid  = threadIdx.x;
    const int nb   = blockIdx.x * BM;
    const int wave = tid >> 6, lane = tid & 63;
    const int wr   = wave >> 1, wc = wave & 1;
    const int lr   = lane & 15, lg = lane >> 4;
    const int sr   = tid >> 2, sq = tid & 3;        // stage: row sr, 64B quarter sq
    const int arow = nb + sr;
    const bool rowok = (arow < N_NODES);

    f32x4 acc[2][4];
#pragma unroll
    for (int i = 0; i < 2; i++)
#pragma unroll
        for (int j = 0; j < 4; j++) acc[i][j] = (f32x4)0.f;

    // prologue: stage et=0 into buf 0
    {
        int2 p = rowok ? pairs[arow * NET] : make_int2(-1, -1);
        uint4v v[4];
        if (p.x >= 0) {
            const uint4v* s0 = (const uint4v*)(xb + (size_t)p.x * C) + sq * 4;
            const uint4v* s1 = (const uint4v*)(xb + (size_t)p.y * C) + sq * 4;
#pragma unroll
            for (int m = 0; m < 4; m++) {
                uint4v a = s0[m], bb = s1[m], o;
                o.x = sumpack(a.x, bb.x); o.y = sumpack(a.y, bb.y);
                o.z = sumpack(a.z, bb.z); o.w = sumpack(a.w, bb.w);
                v[m] = o;
            }
        } else {
            uint4v z = {0u, 0u, 0u, 0u};
            v[0] = z; v[1] = z; v[2] = z; v[3] = z;
        }
        uint4v* dst = (uint4v*)&Alds[0][sr * LDW + sq * 32];
#pragma unroll
        for (int m = 0; m < 4; m++) dst[m] = v[m];
    }
    int2 pn = rowok ? pairs[arow * NET + 1] : make_int2(-1, -1);
    __syncthreads();

    for (int et = 0; et < NET; ++et) {
        const int cur = et & 1;
        const bool doStage = (et + 1 < NET);

        // T14: issue next tile's global loads BEFORE the MFMA phase
        uint4v sa[4], sb[4];
        int2 ps = pn;
        if (doStage && ps.x >= 0) {
            const uint4v* s0 = (const uint4v*)(xb + (size_t)ps.x * C) + sq * 4;
            const uint4v* s1 = (const uint4v*)(xb + (size_t)ps.y * C) + sq * 4;
#pragma unroll
            for (int m = 0; m < 4; m++) { sa[m] = s0[m]; sb[m] = s1[m]; }
        }
        if (et + 2 < NET) pn = rowok ? pairs[arow * NET + et + 2] : make_int2(-1, -1);

        // MFMA phase: B fragments streamed from L2-resident Wf, A from LDS
        const unsigned short* Wet = Wf + (size_t)et * 16384 + (size_t)wc * 8192 + (size_t)lane * 8;
        const unsigned short* A0  = &Alds[cur][(wr * 32 + lr) * LDW + lg * 8];
#pragma unroll
        for (int ks = 0; ks < 4; ++ks) {
            short8 bfr[4];
#pragma unroll
            for (int fn = 0; fn < 4; fn++)
                bfr[fn] = *(const short8*)(Wet + (fn * 4 + ks) * 512);
            short8 af0 = *(const short8*)(A0 + ks * 32);
            short8 af1 = *(const short8*)(A0 + 16 * LDW + ks * 32);
#pragma unroll
            for (int fn = 0; fn < 4; fn++) {
                acc[0][fn] = __builtin_amdgcn_mfma_f32_16x16x32_bf16(af0, bfr[fn], acc[0][fn], 0, 0, 0);
                acc[1][fn] = __builtin_amdgcn_mfma_f32_16x16x32_bf16(af1, bfr[fn], acc[1][fn], 0, 0, 0);
            }
        }

        // finish staging: sum+pack+ds_write AFTER MFMA (loads had the whole phase to land)
        if (doStage) {
            uint4v v[4];
            if (ps.x >= 0) {
#pragma unroll
                for (int m = 0; m < 4; m++) {
                    uint4v o;
                    o.x = sumpack(sa[m].x, sb[m].x); o.y = sumpack(sa[m].y, sb[m].y);
                    o.z = sumpack(sa[m].z, sb[m].z); o.w = sumpack(sa[m].w, sb[m].w);
                    v[m] = o;
                }
            } else {
                uint4v z = {0u, 0u, 0u, 0u};
                v[0] = z; v[1] = z; v[2] = z; v[3] = z;
            }
            uint4v* dst = (uint4v*)&Alds[cur ^ 1][sr * LDW + sq * 32];
#pragma unroll
            for (int m = 0; m < 4; m++) dst[m] = v[m];
        }
        __syncthreads();
    }

    // epilogue: D layout col=lane&15, row=(lane>>4)*4+reg
#pragma unroll
    for (int fm = 0; fm < 2; fm++) {
        int row0 = nb + wr * 32 + fm * 16 + lg * 4;
#pragma unroll
        for (int fn = 0; fn < 4; fn++) {
            int colo = wc * 64 + fn * 16 + lr;
#pragma unroll
            for (int j = 0; j < 4; j++)
                if (row0 + j < N_NODES)
                    out[(size_t)(row0 + j) * C + colo] = acc[fm][fn][j];
        }
    }
}

extern "C" void kernel_launch(void* const* d_in, const int* in_sizes, int n_in,
                              void* d_out, int out_size, void* d_ws, size_t ws_size,
                              hipStream_t stream) {
    const float* x   = (const float*)d_in[0];
    const int*   col = (const int*)d_in[1];
    const int*   idx = (const int*)d_in[2];
    const float* W   = (const float*)d_in[3];
    float* out = (float*)d_out;

    int2* pairs        = (int2*)d_ws;                              // 5.6 MB
    unsigned short* xb = (unsigned short*)(pairs + S_SLOTS);       // 25.6 MB
    unsigned short* Wf = xb + (size_t)N_NODES * C;                 // 1.8 MB

    prep<<<NB_CVTX + NB_CVTW + NB_PAIRS, 256, 0, stream>>>(x, col, idx, W, xb, Wf, pairs);
    fused_mfma<<<(N_NODES + BM - 1) / BM, 256, 0, stream>>>(xb, pairs, Wf, out);
}